// Round 1
// baseline (161.403 us; speedup 1.0000x reference)
//
#include <hip/hip_runtime.h>

// GeodesicLoss: the reference's velocity starts at exactly zero, so
// acc = -einsum(Gamma, v, v) == 0 for every step and traj == outputs
// identically. The whole scan is a no-op; the answer is
//   mean_b || outputs[b] - targets[b] ||_2   (B=524288, D=32).
// christoffel_symbols (d_in[2]) is mathematically dead.

static constexpr int B_ROWS = 524288;  // batch
// D = 32 floats per row = 8 float4 per row.

__global__ __launch_bounds__(256) void geodesic_loss_kernel(
    const float4* __restrict__ o4,
    const float4* __restrict__ t4,
    float* __restrict__ out)
{
    const int tid     = blockIdx.x * blockDim.x + threadIdx.x;
    const int lane8   = threadIdx.x & 7;   // lane within 8-lane row group
    const int group   = tid >> 3;          // global row-group id
    const int ngroups = (gridDim.x * blockDim.x) >> 3;

    float acc = 0.0f;
    for (int r = group; r < B_ROWS; r += ngroups) {
        const int idx = (r << 3) + lane8;  // float4 index: 8 per row
        float4 o = o4[idx];
        float4 t = t4[idx];
        float dx = o.x - t.x;
        float dy = o.y - t.y;
        float dz = o.z - t.z;
        float dw = o.w - t.w;
        float s = dx * dx + dy * dy + dz * dz + dw * dw;
        // reduce squared distance across the 8 lanes of this row group
        s += __shfl_xor(s, 1);
        s += __shfl_xor(s, 2);
        s += __shfl_xor(s, 4);
        if (lane8 == 0) acc += sqrtf(s);
    }

    // sum the 8 group-leaders within the 64-lane wave
    acc += __shfl_xor(acc, 8);
    acc += __shfl_xor(acc, 16);
    acc += __shfl_xor(acc, 32);

    __shared__ float sm[4];                // 4 waves per 256-thread block
    const int wave = threadIdx.x >> 6;
    const int lane = threadIdx.x & 63;
    if (lane == 0) sm[wave] = acc;
    __syncthreads();
    if (threadIdx.x == 0) {
        float total = sm[0] + sm[1] + sm[2] + sm[3];
        atomicAdd(out, total * (1.0f / (float)B_ROWS));
    }
}

extern "C" void kernel_launch(void* const* d_in, const int* in_sizes, int n_in,
                              void* d_out, int out_size, void* d_ws, size_t ws_size,
                              hipStream_t stream) {
    const float4* outputs = (const float4*)d_in[0];
    const float4* targets = (const float4*)d_in[1];
    // d_in[2] (christoffel_symbols) is unused: velocity is identically zero.
    float* out = (float*)d_out;

    // d_out is re-poisoned to 0xAA before every timed launch; zero it.
    hipMemsetAsync(out, 0, sizeof(float), stream);

    // 2048 blocks x 256 threads = 65536 row-groups -> 8 rows per group.
    // Memory-bound: 134 MB read total, perfectly coalesced float4 loads.
    dim3 grid(2048), block(256);
    geodesic_loss_kernel<<<grid, block, 0, stream>>>(outputs, targets, out);
}